// Round 10
// baseline (1182.715 us; speedup 1.0000x reference)
//
#include <hip/hip_runtime.h>

#define NN 50000
#define NE 1000000
#define NBK 196          // buckets of 256 nodes
#define EPB 1024         // edges per place block (256 thr x 4)
#define PB 977           // ceil(NE/EPB)
#define ESTRIDE 5632     // fixed bucket capacity: mean 5102, sigma ~71 -> +7.4 sigma
#define RK 12            // round chunks per bucket (also slice count)

// ---------------- fixed path init: h0 + cursor/sBeg/sLim + arrive ---------
__global__ void init_fixed(const float* __restrict__ x, float* __restrict__ h,
                           int* __restrict__ cursor, int* __restrict__ sBeg,
                           int* __restrict__ sLim, int* __restrict__ arrive) {
    int i = blockIdx.x * 256 + threadIdx.x;
    if (i < NN) h[i] = x[5 * i + 2];
    if (i < NBK) {
        cursor[i] = i * ESTRIDE;
        sBeg[i]   = i * ESTRIDE;
        sLim[i]   = (i + 1) * ESTRIDE;
    }
    if (i < 4 * NBK) arrive[i] = 0;
}

// ---------------- fallback: bucket histogram + h0 init ----------------
__global__ void bucket_count(const int* __restrict__ dst, int* __restrict__ bcnt,
                             const float* __restrict__ x, float* __restrict__ h) {
    __shared__ int hist[NBK];
    int t = threadIdx.x;
    if (t < NBK) hist[t] = 0;
    __syncthreads();
    int gid = blockIdx.x * 256 + t;
    if (gid < NN) h[gid] = x[5 * gid + 2];
#pragma unroll
    for (int j = 0; j < 4; ++j) {
        int e = blockIdx.x * EPB + j * 256 + t;
        if (e < NE) atomicAdd(&hist[dst[e] >> 8], 1);
    }
    __syncthreads();
    if (t < NBK && hist[t]) atomicAdd(&bcnt[t], hist[t]);
}

// ---------------- fallback: scan 196 counts (evenized for uint4 align) ----
__global__ void bucket_scan(const int* __restrict__ bcnt,
                            int* __restrict__ sBeg,
                            int* __restrict__ cursor,
                            int* __restrict__ sLim) {
    __shared__ int part[256];
    int t = threadIdx.x;
    int v = (t < NBK) ? ((bcnt[t] + 1) & ~1) : 0;   // round up to even
    part[t] = v;
    __syncthreads();
    for (int off = 1; off < 256; off <<= 1) {
        int x = part[t];
        int add = (t >= off) ? part[t - off] : 0;
        __syncthreads();
        part[t] = x + add;
        __syncthreads();
    }
    if (t < NBK) {
        int excl = part[t] - v;
        sBeg[t] = excl;
        cursor[t] = excl;
        sLim[t] = 0x7FFFFFFF;   // exact counts: overflow impossible
    }
}

// ---------------- fused MLP + rank + bucket scatter (R6-proven form) ------
__global__ void place_kernel(const float* __restrict__ ea,
                             const int* __restrict__ src,
                             const int* __restrict__ dst,
                             const float* __restrict__ w1,
                             const float* __restrict__ b1,
                             const float* __restrict__ w2,
                             const float* __restrict__ b2,
                             const int* __restrict__ sLim,
                             int* __restrict__ cursor,
                             uint2* __restrict__ es,
                             int dumpbase) {
    __shared__ float sw1[192];
    __shared__ float sb1[64];
    __shared__ float sw2[64];
    __shared__ float sce[EPB];
    __shared__ int hist[NBK];
    __shared__ int hbase[NBK];
    int t = threadIdx.x;
    if (t < 192) sw1[t] = w1[t];
    if (t < 64) { sb1[t] = b1[t]; sw2[t] = w2[t]; }
    if (t < NBK) hist[t] = 0;
    __syncthreads();

    int r[4], dd[4];
#pragma unroll
    for (int j = 0; j < 4; ++j) {
        int e = blockIdx.x * EPB + j * 256 + t;
        dd[j] = -1;
        if (e < NE) {
            float a0 = ea[3 * e + 0];
            float a1 = ea[3 * e + 1];
            float a2 = ea[3 * e + 2];
            float c0 = b2[0], c1 = 0.f, c2 = 0.f, c3 = 0.f;
#pragma unroll
            for (int k = 0; k < 64; k += 4) {
                float h0 = fmaf(a0, sw1[k+0], fmaf(a1, sw1[64+k+0], fmaf(a2, sw1[128+k+0], sb1[k+0])));
                float h1 = fmaf(a0, sw1[k+1], fmaf(a1, sw1[64+k+1], fmaf(a2, sw1[128+k+1], sb1[k+1])));
                float h2 = fmaf(a0, sw1[k+2], fmaf(a1, sw1[64+k+2], fmaf(a2, sw1[128+k+2], sb1[k+2])));
                float h3 = fmaf(a0, sw1[k+3], fmaf(a1, sw1[64+k+3], fmaf(a2, sw1[128+k+3], sb1[k+3])));
                c0 = fmaf(fmaxf(h0, 0.f), sw2[k+0], c0);
                c1 = fmaf(fmaxf(h1, 0.f), sw2[k+1], c1);
                c2 = fmaf(fmaxf(h2, 0.f), sw2[k+2], c2);
                c3 = fmaf(fmaxf(h3, 0.f), sw2[k+3], c3);
            }
            sce[j * 256 + t] = (c0 + c1) + (c2 + c3);
            int d = dst[e];
            dd[j] = d;
            r[j] = atomicAdd(&hist[d >> 8], 1);
        }
    }
    __syncthreads();
    if (t < NBK) { int hv = hist[t]; if (hv) hbase[t] = atomicAdd(&cursor[t], hv); }
    __syncthreads();
#pragma unroll
    for (int j = 0; j < 4; ++j) {
        int e = blockIdx.x * EPB + j * 256 + t;
        if (e < NE) {
            int d = dd[j];
            int b = d >> 8;
            int pos = hbase[b] + r[j];
            if (pos >= sLim[b]) pos = dumpbase + (t & 63);   // overflow guard
            unsigned pack = (unsigned)src[e] | ((unsigned)(d & 255) << 17);
            es[pos] = make_uint2(pack, __float_as_uint(sce[j * 256 + t]));
        }
    }
}

// ---------------- fused round + update (last-arrival epilogue) ------------
// RK blocks per bucket slice-write aggS (agent scope); the last-arriving
// block reduces all RK slices and applies the node update for its 256 nodes.
// Round 1 (isFirst) also counts degree and derives invdeg in the epilogue.
__global__ void round_fused(const int* __restrict__ sBeg,
                            const int* __restrict__ sEnd,
                            const int* __restrict__ sLim,
                            const uint2* __restrict__ es,
                            const float* __restrict__ hold,
                            float* __restrict__ hnew,
                            float* __restrict__ aggS,
                            int* __restrict__ degS,
                            float* __restrict__ invdeg,
                            const float* __restrict__ root,
                            const float* __restrict__ bias,
                            int* __restrict__ arrive,
                            int isFirst) {
    __shared__ float lagg[256];
    __shared__ int ldeg[256];
    __shared__ int lastFlag;
    int t = threadIdx.x;
    int b = blockIdx.x / RK, c = blockIdx.x % RK;
    lagg[t] = 0.f;
    if (isFirst) ldeg[t] = 0;
    __syncthreads();
    int s0 = sBeg[b];
    int s1 = sEnd[b];
    { int cap = sLim[b]; if (s1 > cap) s1 = cap; }
    const uint4* es4 = (const uint4*)es;
    for (int p = s0 + (c * 256 + t) * 2; p < s1; p += RK * 512) {
        uint4 v = es4[p >> 1];
        {
            int sidx = v.x & 0x1FFFF;
            int dl = (v.x >> 17) & 255;
            atomicAdd(&lagg[dl], hold[sidx] * __uint_as_float(v.y));
            if (isFirst) atomicAdd(&ldeg[dl], 1);
        }
        if (p + 1 < s1) {
            int sidx = v.z & 0x1FFFF;
            int dl = (v.z >> 17) & 255;
            atomicAdd(&lagg[dl], hold[sidx] * __uint_as_float(v.w));
            if (isFirst) atomicAdd(&ldeg[dl], 1);
        }
    }
    __syncthreads();
    int node = b * 256 + t;
    if (node < NN) {
        __hip_atomic_store(&aggS[(size_t)c * NN + node], lagg[t],
                           __ATOMIC_RELAXED, __HIP_MEMORY_SCOPE_AGENT);
        if (isFirst)
            __hip_atomic_store(&degS[(size_t)c * NN + node], ldeg[t],
                               __ATOMIC_RELAXED, __HIP_MEMORY_SCOPE_AGENT);
    }
    __threadfence();
    if (t == 0) {
        int prev = __hip_atomic_fetch_add(&arrive[b], 1,
                                          __ATOMIC_ACQ_REL, __HIP_MEMORY_SCOPE_AGENT);
        lastFlag = (prev == RK - 1);
    }
    __syncthreads();
    if (!lastFlag) return;
    // last block for bucket b: reduce slices, update its 256 nodes
    __threadfence();
    if (node < NN) {
        float a = 0.f;
        int d = 0;
#pragma unroll
        for (int cc = 0; cc < RK; ++cc) {
            a += __hip_atomic_load(&aggS[(size_t)cc * NN + node],
                                   __ATOMIC_RELAXED, __HIP_MEMORY_SCOPE_AGENT);
            if (isFirst)
                d += __hip_atomic_load(&degS[(size_t)cc * NN + node],
                                       __ATOMIC_RELAXED, __HIP_MEMORY_SCOPE_AGENT);
        }
        float inv;
        if (isFirst) { inv = (d > 0) ? (1.0f / (float)d) : 0.f; invdeg[node] = inv; }
        else inv = invdeg[node];
        hnew[node] = fmaxf(fmaf(hold[node], root[0], fmaf(a, inv, bias[0])), 0.f);
    }
}

// ================= launch =================

extern "C" void kernel_launch(void* const* d_in, const int* in_sizes, int n_in,
                              void* d_out, int out_size, void* d_ws, size_t ws_size,
                              hipStream_t stream) {
    const float* x    = (const float*)d_in[0];
    const int*   ei   = (const int*)d_in[1];
    const float* ea   = (const float*)d_in[2];
    const float* w1   = (const float*)d_in[3];
    const float* b1   = (const float*)d_in[4];
    const float* w2   = (const float*)d_in[5];
    const float* b2   = (const float*)d_in[6];
    const float* root = (const float*)d_in[7];
    const float* bias = (const float*)d_in[8];

    const int* src = ei;
    const int* dst = ei + NE;
    float* h = (float*)d_out;   // h0, h2, h4 live here (final in d_out)

    const int BLK = 256;
    const int gR = NBK * RK;    // 2352

    const size_t esFixed = (size_t)NBK * ESTRIDE + 64;   // entries incl dump
    const size_t needFixed = esFixed * 8
                           + (size_t)(NBK * 7) * 4               // cursor,sBeg,sLim,arrive[4*NBK]
                           + (size_t)RK * NN * 4 * 2             // aggS, degS
                           + (size_t)NN * 4 * 2;                 // invdeg, hB

    if (ws_size >= needFixed) {
        // -------- fixed-capacity path: no count, no scan, no memset --------
        uint2* es     = (uint2*)d_ws;
        int*   cursor = (int*)(es + esFixed);
        int*   sBeg   = cursor + NBK;
        int*   sLim   = sBeg + NBK;
        int*   arrive = sLim + NBK;                    // 4*NBK
        float* aggS   = (float*)(arrive + 4 * NBK);
        int*   degS   = (int*)(aggS + (size_t)RK * NN);
        float* invdeg = (float*)(degS + (size_t)RK * NN);
        float* hB     = invdeg + NN;

        init_fixed<<<NBK, BLK, 0, stream>>>(x, h, cursor, sBeg, sLim, arrive);
        place_kernel<<<PB, BLK, 0, stream>>>(ea, src, dst, w1, b1, w2, b2,
                                             sLim, cursor, es, (int)(NBK * ESTRIDE));
        round_fused<<<gR, BLK, 0, stream>>>(sBeg, cursor, sLim, es, h,  hB, aggS,
                                            degS, invdeg, root, bias, arrive + 0 * NBK, 1);
        round_fused<<<gR, BLK, 0, stream>>>(sBeg, cursor, sLim, es, hB, h,  aggS,
                                            degS, invdeg, root, bias, arrive + 1 * NBK, 0);
        round_fused<<<gR, BLK, 0, stream>>>(sBeg, cursor, sLim, es, h,  hB, aggS,
                                            degS, invdeg, root, bias, arrive + 2 * NBK, 0);
        round_fused<<<gR, BLK, 0, stream>>>(sBeg, cursor, sLim, es, hB, h,  aggS,
                                            degS, invdeg, root, bias, arrive + 3 * NBK, 0);
    } else {
        // -------- fallback: exact counts via count+scan (tight, evenized) --
        uint2* es     = (uint2*)d_ws;                  // NE + NBK entries
        int*   bcnt   = (int*)(es + NE + NBK);         // NBK  } zeroed together
        int*   arrive = bcnt + NBK;                    // 4*NBK }
        int*   cursor = arrive + 4 * NBK;
        int*   sBeg   = cursor + NBK;
        int*   sLim   = sBeg + NBK;
        float* aggS   = (float*)(sLim + NBK);
        int*   degS   = (int*)(aggS + (size_t)RK * NN);
        float* invdeg = (float*)(degS + (size_t)RK * NN);
        float* hB     = invdeg + NN;

        hipMemsetAsync(bcnt, 0, 5 * NBK * 4, stream);
        bucket_count<<<PB, BLK, 0, stream>>>(dst, bcnt, x, h);
        bucket_scan<<<1, 256, 0, stream>>>(bcnt, sBeg, cursor, sLim);
        place_kernel<<<PB, BLK, 0, stream>>>(ea, src, dst, w1, b1, w2, b2,
                                             sLim, cursor, es, 0);
        round_fused<<<gR, BLK, 0, stream>>>(sBeg, cursor, sLim, es, h,  hB, aggS,
                                            degS, invdeg, root, bias, arrive + 0 * NBK, 1);
        round_fused<<<gR, BLK, 0, stream>>>(sBeg, cursor, sLim, es, hB, h,  aggS,
                                            degS, invdeg, root, bias, arrive + 1 * NBK, 0);
        round_fused<<<gR, BLK, 0, stream>>>(sBeg, cursor, sLim, es, h,  hB, aggS,
                                            degS, invdeg, root, bias, arrive + 2 * NBK, 0);
        round_fused<<<gR, BLK, 0, stream>>>(sBeg, cursor, sLim, es, hB, h,  aggS,
                                            degS, invdeg, root, bias, arrive + 3 * NBK, 0);
    }
}

// Round 11
// 165.575 us; speedup vs baseline: 7.1431x; 7.1431x over previous
//
#include <hip/hip_runtime.h>

#define NN 50000
#define NE 1000000
#define NBK 196          // buckets of 256 nodes
#define EPB 1024         // edges per place block (256 thr x 4)
#define PB 977           // ceil(NE/EPB)
#define ESTRIDE 5632     // fixed bucket capacity: mean 5102, sigma ~71 -> +7.4 sigma
#define RK 12            // round chunks per bucket (also slice count)

// ---------------- fixed path init: h0 + cursor/sBeg/sLim ----------------
__global__ void init_fixed(const float* __restrict__ x, float* __restrict__ h,
                           int* __restrict__ cursor, int* __restrict__ sBeg,
                           int* __restrict__ sLim) {
    int i = blockIdx.x * 256 + threadIdx.x;
    if (i < NN) h[i] = x[5 * i + 2];
    if (i < NBK) {
        cursor[i] = i * ESTRIDE;
        sBeg[i]   = i * ESTRIDE;
        sLim[i]   = (i + 1) * ESTRIDE;
    }
}

// ---------------- fallback: bucket histogram + h0 init ----------------
__global__ void bucket_count(const int* __restrict__ dst, int* __restrict__ bcnt,
                             const float* __restrict__ x, float* __restrict__ h) {
    __shared__ int hist[NBK];
    int t = threadIdx.x;
    if (t < NBK) hist[t] = 0;
    __syncthreads();
    int gid = blockIdx.x * 256 + t;
    if (gid < NN) h[gid] = x[5 * gid + 2];
#pragma unroll
    for (int j = 0; j < 4; ++j) {
        int e = blockIdx.x * EPB + j * 256 + t;
        if (e < NE) atomicAdd(&hist[dst[e] >> 8], 1);
    }
    __syncthreads();
    if (t < NBK && hist[t]) atomicAdd(&bcnt[t], hist[t]);
}

// ---------------- fallback: scan 196 counts (evenized for uint4 align) ----
__global__ void bucket_scan(const int* __restrict__ bcnt,
                            int* __restrict__ sBeg,
                            int* __restrict__ cursor,
                            int* __restrict__ sLim) {
    __shared__ int part[256];
    int t = threadIdx.x;
    int v = (t < NBK) ? ((bcnt[t] + 1) & ~1) : 0;   // round up to even
    part[t] = v;
    __syncthreads();
    for (int off = 1; off < 256; off <<= 1) {
        int x = part[t];
        int add = (t >= off) ? part[t - off] : 0;
        __syncthreads();
        part[t] = x + add;
        __syncthreads();
    }
    if (t < NBK) {
        int excl = part[t] - v;
        sBeg[t] = excl;
        cursor[t] = excl;
        sLim[t] = 0x7FFFFFFF;   // exact counts: overflow impossible
    }
}

// ---------------- fused MLP + rank + bucket scatter (R6-proven form) ------
__global__ void place_kernel(const float* __restrict__ ea,
                             const int* __restrict__ src,
                             const int* __restrict__ dst,
                             const float* __restrict__ w1,
                             const float* __restrict__ b1,
                             const float* __restrict__ w2,
                             const float* __restrict__ b2,
                             const int* __restrict__ sLim,
                             int* __restrict__ cursor,
                             uint2* __restrict__ es,
                             int dumpbase) {
    __shared__ float sw1[192];
    __shared__ float sb1[64];
    __shared__ float sw2[64];
    __shared__ float sce[EPB];
    __shared__ int hist[NBK];
    __shared__ int hbase[NBK];
    int t = threadIdx.x;
    if (t < 192) sw1[t] = w1[t];
    if (t < 64) { sb1[t] = b1[t]; sw2[t] = w2[t]; }
    if (t < NBK) hist[t] = 0;
    __syncthreads();

    int r[4], dd[4];
#pragma unroll
    for (int j = 0; j < 4; ++j) {
        int e = blockIdx.x * EPB + j * 256 + t;
        dd[j] = -1;
        if (e < NE) {
            float a0 = ea[3 * e + 0];
            float a1 = ea[3 * e + 1];
            float a2 = ea[3 * e + 2];
            float c0 = b2[0], c1 = 0.f, c2 = 0.f, c3 = 0.f;
#pragma unroll
            for (int k = 0; k < 64; k += 4) {
                float h0 = fmaf(a0, sw1[k+0], fmaf(a1, sw1[64+k+0], fmaf(a2, sw1[128+k+0], sb1[k+0])));
                float h1 = fmaf(a0, sw1[k+1], fmaf(a1, sw1[64+k+1], fmaf(a2, sw1[128+k+1], sb1[k+1])));
                float h2 = fmaf(a0, sw1[k+2], fmaf(a1, sw1[64+k+2], fmaf(a2, sw1[128+k+2], sb1[k+2])));
                float h3 = fmaf(a0, sw1[k+3], fmaf(a1, sw1[64+k+3], fmaf(a2, sw1[128+k+3], sb1[k+3])));
                c0 = fmaf(fmaxf(h0, 0.f), sw2[k+0], c0);
                c1 = fmaf(fmaxf(h1, 0.f), sw2[k+1], c1);
                c2 = fmaf(fmaxf(h2, 0.f), sw2[k+2], c2);
                c3 = fmaf(fmaxf(h3, 0.f), sw2[k+3], c3);
            }
            sce[j * 256 + t] = (c0 + c1) + (c2 + c3);
            int d = dst[e];
            dd[j] = d;
            r[j] = atomicAdd(&hist[d >> 8], 1);
        }
    }
    __syncthreads();
    if (t < NBK) { int hv = hist[t]; if (hv) hbase[t] = atomicAdd(&cursor[t], hv); }
    __syncthreads();
#pragma unroll
    for (int j = 0; j < 4; ++j) {
        int e = blockIdx.x * EPB + j * 256 + t;
        if (e < NE) {
            int d = dd[j];
            int b = d >> 8;
            int pos = hbase[b] + r[j];
            if (pos >= sLim[b]) pos = dumpbase + (t & 63);   // overflow guard
            unsigned pack = (unsigned)src[e] | ((unsigned)(d & 255) << 17);
            es[pos] = make_uint2(pack, __float_as_uint(sce[j * 256 + t]));
        }
    }
}

// ---------------- round 1: slice-write agg + deg (no global atomics) ------
__global__ void round1_slice(const int* __restrict__ sBeg,
                             const int* __restrict__ sEnd,
                             const int* __restrict__ sLim,
                             const uint2* __restrict__ es,
                             const float* __restrict__ hold,
                             float* __restrict__ aggS,
                             int* __restrict__ degS) {
    __shared__ float lagg[256];
    __shared__ int ldeg[256];
    int t = threadIdx.x;
    int b = blockIdx.x / RK, c = blockIdx.x % RK;
    lagg[t] = 0.f;
    ldeg[t] = 0;
    __syncthreads();
    int s0 = sBeg[b];
    int s1 = sEnd[b];
    { int cap = sLim[b]; if (s1 > cap) s1 = cap; }
    const uint4* es4 = (const uint4*)es;
    for (int p = s0 + (c * 256 + t) * 2; p < s1; p += RK * 512) {
        uint4 v = es4[p >> 1];
        {
            int sidx = v.x & 0x1FFFF;
            int dl = (v.x >> 17) & 255;
            atomicAdd(&lagg[dl], hold[sidx] * __uint_as_float(v.y));
            atomicAdd(&ldeg[dl], 1);
        }
        if (p + 1 < s1) {
            int sidx = v.z & 0x1FFFF;
            int dl = (v.z >> 17) & 255;
            atomicAdd(&lagg[dl], hold[sidx] * __uint_as_float(v.w));
            atomicAdd(&ldeg[dl], 1);
        }
    }
    __syncthreads();
    int node = b * 256 + t;
    if (node < NN) {
        aggS[(size_t)c * NN + node] = lagg[t];
        degS[(size_t)c * NN + node] = ldeg[t];
    }
}

// ---------------- rounds 2..4: slice-write agg ----------------
__global__ void round_slice(const int* __restrict__ sBeg,
                            const int* __restrict__ sEnd,
                            const int* __restrict__ sLim,
                            const uint2* __restrict__ es,
                            const float* __restrict__ hold,
                            float* __restrict__ aggS) {
    __shared__ float lagg[256];
    int t = threadIdx.x;
    int b = blockIdx.x / RK, c = blockIdx.x % RK;
    lagg[t] = 0.f;
    __syncthreads();
    int s0 = sBeg[b];
    int s1 = sEnd[b];
    { int cap = sLim[b]; if (s1 > cap) s1 = cap; }
    const uint4* es4 = (const uint4*)es;
    for (int p = s0 + (c * 256 + t) * 2; p < s1; p += RK * 512) {
        uint4 v = es4[p >> 1];
        {
            int sidx = v.x & 0x1FFFF;
            int dl = (v.x >> 17) & 255;
            atomicAdd(&lagg[dl], hold[sidx] * __uint_as_float(v.y));
        }
        if (p + 1 < s1) {
            int sidx = v.z & 0x1FFFF;
            int dl = (v.z >> 17) & 255;
            atomicAdd(&lagg[dl], hold[sidx] * __uint_as_float(v.w));
        }
    }
    __syncthreads();
    int node = b * 256 + t;
    if (node < NN) aggS[(size_t)c * NN + node] = lagg[t];
}

// ---------------- update 1: sum slices (2 nodes/thread), invdeg, update ----
__global__ void update1(const int* __restrict__ degS,
                        const float* __restrict__ aggS,
                        float* __restrict__ invdeg,
                        const float* __restrict__ hold,
                        float* __restrict__ hnew,
                        const float* __restrict__ root,
                        const float* __restrict__ bias) {
    int i = (blockIdx.x * blockDim.x + threadIdx.x) * 2;
    if (i >= NN) return;
    float2 a = make_float2(0.f, 0.f);
    int2 d = make_int2(0, 0);
#pragma unroll
    for (int c = 0; c < RK; ++c) {
        float2 av = *(const float2*)&aggS[(size_t)c * NN + i];
        int2 dv = *(const int2*)&degS[(size_t)c * NN + i];
        a.x += av.x; a.y += av.y;
        d.x += dv.x; d.y += dv.y;
    }
    float rt = root[0], bs = bias[0];
    float2 hv = *(const float2*)&hold[i];
    float inv0 = (d.x > 0) ? (1.0f / (float)d.x) : 0.f;
    float inv1 = (d.y > 0) ? (1.0f / (float)d.y) : 0.f;
    *(float2*)&invdeg[i] = make_float2(inv0, inv1);
    float o0 = fmaxf(fmaf(hv.x, rt, fmaf(a.x, inv0, bs)), 0.f);
    float o1 = fmaxf(fmaf(hv.y, rt, fmaf(a.y, inv1, bs)), 0.f);
    *(float2*)&hnew[i] = make_float2(o0, o1);
}

// ---------------- updates 2..4: sum slices (2 nodes/thread), update --------
__global__ void update_kernel(const float* __restrict__ aggS,
                              const float* __restrict__ invdeg,
                              const float* __restrict__ hold,
                              float* __restrict__ hnew,
                              const float* __restrict__ root,
                              const float* __restrict__ bias) {
    int i = (blockIdx.x * blockDim.x + threadIdx.x) * 2;
    if (i >= NN) return;
    float2 a = make_float2(0.f, 0.f);
#pragma unroll
    for (int c = 0; c < RK; ++c) {
        float2 av = *(const float2*)&aggS[(size_t)c * NN + i];
        a.x += av.x; a.y += av.y;
    }
    float rt = root[0], bs = bias[0];
    float2 hv = *(const float2*)&hold[i];
    float2 iv = *(const float2*)&invdeg[i];
    float o0 = fmaxf(fmaf(hv.x, rt, fmaf(a.x, iv.x, bs)), 0.f);
    float o1 = fmaxf(fmaf(hv.y, rt, fmaf(a.y, iv.y, bs)), 0.f);
    *(float2*)&hnew[i] = make_float2(o0, o1);
}

// ================= launch =================

extern "C" void kernel_launch(void* const* d_in, const int* in_sizes, int n_in,
                              void* d_out, int out_size, void* d_ws, size_t ws_size,
                              hipStream_t stream) {
    const float* x    = (const float*)d_in[0];
    const int*   ei   = (const int*)d_in[1];
    const float* ea   = (const float*)d_in[2];
    const float* w1   = (const float*)d_in[3];
    const float* b1   = (const float*)d_in[4];
    const float* w2   = (const float*)d_in[5];
    const float* b2   = (const float*)d_in[6];
    const float* root = (const float*)d_in[7];
    const float* bias = (const float*)d_in[8];

    const int* src = ei;
    const int* dst = ei + NE;
    float* h = (float*)d_out;   // h0, h2, h4 live here (final in d_out)

    const int BLK = 256;
    const int gN2 = (NN / 2 + BLK - 1) / BLK;   // 98 (2 nodes/thread)
    const int gR = NBK * RK;    // 2352

    const size_t esFixed = (size_t)NBK * ESTRIDE + 64;   // entries incl dump
    const size_t needFixed = esFixed * 8
                           + (size_t)(NBK * 3) * 4               // cursor,sBeg,sLim
                           + (size_t)RK * NN * 4 * 2             // aggS, degS
                           + (size_t)NN * 4 * 2;                 // invdeg, hB

    if (ws_size >= needFixed) {
        // -------- fixed-capacity path: no count, no scan, no memset --------
        uint2* es     = (uint2*)d_ws;
        int*   cursor = (int*)(es + esFixed);
        int*   sBeg   = cursor + NBK;
        int*   sLim   = sBeg + NBK;
        float* aggS   = (float*)(sLim + NBK);
        int*   degS   = (int*)(aggS + (size_t)RK * NN);
        float* invdeg = (float*)(degS + (size_t)RK * NN);
        float* hB     = invdeg + NN;

        init_fixed<<<NBK, BLK, 0, stream>>>(x, h, cursor, sBeg, sLim);
        place_kernel<<<PB, BLK, 0, stream>>>(ea, src, dst, w1, b1, w2, b2,
                                             sLim, cursor, es, (int)(NBK * ESTRIDE));
        round1_slice<<<gR, BLK, 0, stream>>>(sBeg, cursor, sLim, es, h, aggS, degS);
        update1<<<gN2, BLK, 0, stream>>>(degS, aggS, invdeg, h, hB, root, bias);
        round_slice<<<gR, BLK, 0, stream>>>(sBeg, cursor, sLim, es, hB, aggS);
        update_kernel<<<gN2, BLK, 0, stream>>>(aggS, invdeg, hB, h, root, bias);
        round_slice<<<gR, BLK, 0, stream>>>(sBeg, cursor, sLim, es, h, aggS);
        update_kernel<<<gN2, BLK, 0, stream>>>(aggS, invdeg, h, hB, root, bias);
        round_slice<<<gR, BLK, 0, stream>>>(sBeg, cursor, sLim, es, hB, aggS);
        update_kernel<<<gN2, BLK, 0, stream>>>(aggS, invdeg, hB, h, root, bias);
    } else {
        // -------- fallback: exact counts via count+scan (tight, evenized) --
        uint2* es     = (uint2*)d_ws;                    // NE + NBK entries
        int*   bcnt   = (int*)(es + NE + NBK);
        int*   cursor = bcnt + NBK;
        int*   sBeg   = cursor + NBK;
        int*   sLim   = sBeg + NBK;
        float* aggS   = (float*)(sLim + NBK);
        int*   degS   = (int*)(aggS + (size_t)RK * NN);
        float* invdeg = (float*)(degS + (size_t)RK * NN);
        float* hB     = invdeg + NN;

        hipMemsetAsync(bcnt, 0, NBK * 4, stream);
        bucket_count<<<PB, BLK, 0, stream>>>(dst, bcnt, x, h);
        bucket_scan<<<1, 256, 0, stream>>>(bcnt, sBeg, cursor, sLim);
        place_kernel<<<PB, BLK, 0, stream>>>(ea, src, dst, w1, b1, w2, b2,
                                             sLim, cursor, es, 0);
        round1_slice<<<gR, BLK, 0, stream>>>(sBeg, cursor, sLim, es, h, aggS, degS);
        update1<<<gN2, BLK, 0, stream>>>(degS, aggS, invdeg, h, hB, root, bias);
        round_slice<<<gR, BLK, 0, stream>>>(sBeg, cursor, sLim, es, hB, aggS);
        update_kernel<<<gN2, BLK, 0, stream>>>(aggS, invdeg, hB, h, root, bias);
        round_slice<<<gR, BLK, 0, stream>>>(sBeg, cursor, sLim, es, h, aggS);
        update_kernel<<<gN2, BLK, 0, stream>>>(aggS, invdeg, h, hB, root, bias);
        round_slice<<<gR, BLK, 0, stream>>>(sBeg, cursor, sLim, es, hB, aggS);
        update_kernel<<<gN2, BLK, 0, stream>>>(aggS, invdeg, hB, h, root, bias);
    }
}